// Round 4
// baseline (353.165 us; speedup 1.0000x reference)
//
#include <hip/hip_runtime.h>

#define N_NODES 50000
#define N_EDGES 600000

using bf16x8 = __attribute__((ext_vector_type(8))) short;
using f32x4  = __attribute__((ext_vector_type(4))) float;
typedef unsigned int uint32_tt;

__device__ __forceinline__ unsigned short f2bf(float f) {
    union { float f; unsigned int u; } v; v.f = f;
    unsigned int u = v.u;
    return (unsigned short)((u + 0x7fffu + ((u >> 16) & 1u)) >> 16);  // RNE
}
__device__ __forceinline__ float bf2f(unsigned int h16) {
    union { unsigned int u; float f; } v; v.u = h16 << 16;
    return v.f;
}

// ---------------- CSR build ----------------

__global__ void hist_kernel(const int* __restrict__ ei, int* __restrict__ cnt, int E) {
    int e = blockIdx.x * 256 + threadIdx.x;
    if (e < E) atomicAdd(&cnt[ei[E + e]], 1);
}

__global__ void scan1(const int* __restrict__ deg, int* __restrict__ out,
                      int* __restrict__ bsum, int n) {
    __shared__ int s[256];
    int t = threadIdx.x;
    int base = blockIdx.x * 1024 + t * 4;
    int v0 = (base + 0 < n) ? deg[base + 0] : 0;
    int v1 = (base + 1 < n) ? deg[base + 1] : 0;
    int v2 = (base + 2 < n) ? deg[base + 2] : 0;
    int v3 = (base + 3 < n) ? deg[base + 3] : 0;
    int tsum = v0 + v1 + v2 + v3;
    s[t] = tsum;
    __syncthreads();
    for (int off = 1; off < 256; off <<= 1) {
        int tmp = (t >= off) ? s[t - off] : 0;
        __syncthreads();
        s[t] += tmp;
        __syncthreads();
    }
    int excl = s[t] - tsum;
    if (base + 0 < n) out[base + 0] = excl;
    if (base + 1 < n) out[base + 1] = excl + v0;
    if (base + 2 < n) out[base + 2] = excl + v0 + v1;
    if (base + 3 < n) out[base + 3] = excl + v0 + v1 + v2;
    if (t == 255) bsum[blockIdx.x] = s[255];
}

__global__ void scan2(int* __restrict__ bsum, int nb) {
    if (threadIdx.x == 0 && blockIdx.x == 0) {
        int acc = 0;
        for (int i = 0; i < nb; ++i) { int v = bsum[i]; bsum[i] = acc; acc += v; }
    }
}

__global__ void scan3(int* __restrict__ off, const int* __restrict__ bsum, int n, int E) {
    int i = blockIdx.x * 256 + threadIdx.x;
    if (i < n) off[i] += bsum[i >> 10];
    if (i == n) off[n] = E;
}

// packed edge metadata: {src, f32bits(cr), f32bits(ci), 0} — ONE random 16B
// write stream instead of three 4B streams
__global__ void scatter_kernel(const int* __restrict__ ei, const float* __restrict__ w,
                               const float* __restrict__ sim, const int* __restrict__ off,
                               int* __restrict__ cnt, uint4* __restrict__ edat, int E) {
    int e = blockIdx.x * 256 + threadIdx.x;
    if (e >= E) return;
    int s = ei[e], d = ei[E + e];
    int p = off[d] + atomicAdd(&cnt[d], 1);
    float wt = w[e];
    uint4 m;
    m.x = (unsigned)s;
    m.y = __float_as_uint(wt * sim[2 * e]);
    m.z = __float_as_uint(wt * sim[2 * e + 1]);
    m.w = 0u;
    edat[p] = m;
}

// ---------------- prep: x -> bf16 padded [N][96]; weight pack ----------------

__global__ void convert_x(const float* __restrict__ x0, unsigned short* __restrict__ xb, int n) {
    int i = blockIdx.x * 256 + threadIdx.x;
    if (i >= n * 96) return;
    int r = i / 96, c = i - r * 96;
    xb[i] = (c < 75) ? f2bf(x0[r * 75 + c]) : (unsigned short)0;
}

// BT[n][part*CINP + k] = {wr[k][n], -wi[k][n], lw[n][k]}  (bf16, zero-padded k>=CIN)
__global__ void build_bt(const float* __restrict__ wr, const float* __restrict__ wi,
                         const float* __restrict__ lw, unsigned short* __restrict__ BT,
                         int CIN, int CINP, int COUT) {
    int KTOT = 3 * CINP;
    int i = blockIdx.x * 256 + threadIdx.x;
    if (i >= COUT * KTOT) return;
    int nn = i / KTOT, k = i - nn * KTOT;
    int part = k / CINP, kk = k - part * CINP;
    float v = 0.f;
    if (kk < CIN) {
        if (part == 0)      v = wr[kk * COUT + nn];
        else if (part == 1) v = -wi[kk * COUT + nn];
        else                v = lw[nn * CIN + kk];
    }
    BT[i] = f2bf(v);
}

// ---------------- aggregation: one wave per node, batched-8 gathers ----------
// Every batch (incl. tail) issues 8 back-to-back gathers before any FMA; tail
// slots clamp to the last valid edge (dup gathers L1-hit, coeff forced to 0).
// Next batch's metadata loads issue after the gathers, before the FMAs, so the
// meta->gather serial chain is paid once per node, not per batch.
template <int CU2>  // uint32s per feature row (= CINP/2)
__global__ __launch_bounds__(256) void agg_bf16(
    const uint32_tt* __restrict__ x, const int* __restrict__ off,
    const uint4* __restrict__ edat, uint32_tt* __restrict__ aggR,
    uint32_tt* __restrict__ aggI, int n) {
    int wave = threadIdx.x >> 6;
    int lane = threadIdx.x & 63;
    int node = blockIdx.x * 4 + wave;
    if (node >= n) return;
    int lc = (CU2 == 64) ? lane : (lane < CU2 ? lane : CU2 - 1);  // clamped lane
    float arl = 0.f, arh = 0.f, ail = 0.f, aih = 0.f;
    int e0 = off[node], e1 = off[node + 1];

    if (e0 < e1) {
        uint4 m[8], mn[8];
        int rem0 = e1 - e0; if (rem0 > 8) rem0 = 8;
#pragma unroll
        for (int j = 0; j < 8; ++j) m[j] = edat[e0 + (j < rem0 ? j : rem0 - 1)];
        for (int e = e0; e < e1; e += 8) {
            // 8 independent gathers in flight
            uint32_tt w[8];
#pragma unroll
            for (int j = 0; j < 8; ++j) w[j] = x[(size_t)m[j].x * CU2 + lc];
            // prefetch next batch's metadata (overlaps gather latency)
            int en = e + 8;
            if (en < e1) {
                int remn = e1 - en; if (remn > 8) remn = 8;
#pragma unroll
                for (int j = 0; j < 8; ++j) mn[j] = edat[en + (j < remn ? j : remn - 1)];
            }
            int remc = e1 - e; if (remc > 8) remc = 8;
#pragma unroll
            for (int j = 0; j < 8; ++j) {
                float cr = (j < remc) ? __uint_as_float(m[j].y) : 0.f;
                float ci = (j < remc) ? __uint_as_float(m[j].z) : 0.f;
                float lo = bf2f(w[j] & 0xffffu), hi = bf2f(w[j] >> 16);
                arl += cr * lo; arh += cr * hi;
                ail += ci * lo; aih += ci * hi;
            }
#pragma unroll
            for (int j = 0; j < 8; ++j) m[j] = mn[j];
        }
    }
    if (lane < CU2) {
        aggR[(size_t)node * CU2 + lane] = (uint32_tt)f2bf(arl) | ((uint32_tt)f2bf(arh) << 16);
        aggI[(size_t)node * CU2 + lane] = (uint32_tt)f2bf(ail) | ((uint32_tt)f2bf(aih) << 16);
    }
}

// ---------------- bf16 MFMA GEMM: out = relu([aggR|aggI|x] @ BT^T + cb + lb) --
template <int CINP, int COUT, int BM, int WM, int WN, int MT, int NT, bool OUT_BF16>
__global__ __launch_bounds__(256) void gemm_mfma(
    const unsigned short* __restrict__ A0, const unsigned short* __restrict__ A1,
    const unsigned short* __restrict__ A2, const unsigned short* __restrict__ BT,
    const float* __restrict__ cb, const float* __restrict__ lb,
    void* __restrict__ outv, int n) {
    constexpr int PK = 40;              // padded k-stride (bf16): 80B rows -> 2-way banks
    constexpr int KTOT = 3 * CINP;
    constexpr int NCH = KTOT / 32;      // K chunks
    constexpr int CPP = CINP / 32;      // chunks per part
    __shared__ unsigned short sA[BM][PK];
    __shared__ unsigned short sB[COUT][PK];

    int t = threadIdx.x;
    int lane = t & 63, wave = t >> 6;
    int wm = wave / WN, wn = wave % WN;
    int ml = lane & 15, kh = lane >> 4;   // kh in [0,4)
    int node0 = blockIdx.x * BM;

    const unsigned short* Asrc[3] = {A0, A1, A2};

    f32x4 acc[MT][NT];
#pragma unroll
    for (int mt = 0; mt < MT; ++mt)
#pragma unroll
        for (int nt = 0; nt < NT; ++nt) acc[mt][nt] = (f32x4){0.f, 0.f, 0.f, 0.f};

    for (int c = 0; c < NCH; ++c) {
        int part = c / CPP;
        int kk = (c - part * CPP) * 32;
        const unsigned short* __restrict__ Ap = Asrc[part];
        __syncthreads();
#pragma unroll
        for (int i = t; i < BM * 4; i += 256) {
            int r = i >> 2, q = i & 3;
            int node = node0 + r;
            if (node >= n) node = n - 1;  // clamp: garbage rows never written out
            *(uint4*)&sA[r][q * 8] =
                *(const uint4*)(Ap + (size_t)node * CINP + kk + q * 8);
        }
#pragma unroll
        for (int i = t; i < COUT * 4; i += 256) {
            int r = i >> 2, q = i & 3;
            *(uint4*)&sB[r][q * 8] =
                *(const uint4*)(BT + (size_t)r * KTOT + c * 32 + q * 8);
        }
        __syncthreads();
        bf16x8 af[MT], bfr[NT];
#pragma unroll
        for (int mt = 0; mt < MT; ++mt)
            af[mt] = *(const bf16x8*)&sA[wm * (MT * 16) + mt * 16 + ml][kh * 8];
#pragma unroll
        for (int nt = 0; nt < NT; ++nt)
            bfr[nt] = *(const bf16x8*)&sB[wn * (NT * 16) + nt * 16 + ml][kh * 8];
#pragma unroll
        for (int mt = 0; mt < MT; ++mt)
#pragma unroll
            for (int nt = 0; nt < NT; ++nt)
                acc[mt][nt] = __builtin_amdgcn_mfma_f32_16x16x32_bf16(
                    af[mt], bfr[nt], acc[mt][nt], 0, 0, 0);
    }

    // epilogue: C/D layout col=lane&15, row=(lane>>4)*4+reg  [m89-verified]
    int row0 = kh * 4;
#pragma unroll
    for (int nt = 0; nt < NT; ++nt) {
        int col = wn * (NT * 16) + nt * 16 + ml;
        float bias = cb[col] + lb[col];
#pragma unroll
        for (int mt = 0; mt < MT; ++mt) {
#pragma unroll
            for (int r = 0; r < 4; ++r) {
                int node = node0 + wm * (MT * 16) + mt * 16 + row0 + r;
                if (node < n) {
                    float v = acc[mt][nt][r] + bias;
                    v = v > 0.f ? v : 0.f;
                    if (OUT_BF16)
                        ((unsigned short*)outv)[(size_t)node * COUT + col] = f2bf(v);
                    else
                        ((float*)outv)[(size_t)node * COUT + col] = v;
                }
            }
        }
    }
}

// ---------------- launch ----------------

extern "C" void kernel_launch(void* const* d_in, const int* in_sizes, int n_in,
                              void* d_out, int out_size, void* d_ws, size_t ws_size,
                              hipStream_t stream) {
    const float* x0  = (const float*)d_in[0];
    const int*   ei  = (const int*)d_in[1];
    const float* wgt = (const float*)d_in[2];
    const float* sim = (const float*)d_in[3];
    const float *wr[3], *wi[3], *cb[3], *lw[3], *lb[3];
    for (int l = 0; l < 3; ++l) {
        wr[l] = (const float*)d_in[4 + 5 * l];
        wi[l] = (const float*)d_in[5 + 5 * l];
        cb[l] = (const float*)d_in[6 + 5 * l];
        lw[l] = (const float*)d_in[7 + 5 * l];
        lb[l] = (const float*)d_in[8 + 5 * l];
    }

    char* p = (char*)d_ws;
    auto alloc = [&](size_t bytes) -> void* {
        void* r = p;
        p += (bytes + 255) & ~(size_t)255;
        return r;
    };
    int*   off  = (int*)alloc((N_NODES + 1) * 4);
    int*   cnt  = (int*)alloc(N_NODES * 4);
    int*   bsum = (int*)alloc(256);
    uint4* edat = (uint4*)alloc((size_t)N_EDGES * 16);
    unsigned short* xb    = (unsigned short*)alloc((size_t)N_NODES * 96 * 2);
    unsigned short* aggRb = (unsigned short*)alloc((size_t)N_NODES * 128 * 2);
    unsigned short* aggIb = (unsigned short*)alloc((size_t)N_NODES * 128 * 2);
    unsigned short* h1b   = (unsigned short*)alloc((size_t)N_NODES * 128 * 2);
    unsigned short* h2b   = (unsigned short*)alloc((size_t)N_NODES * 128 * 2);
    unsigned short* BT0   = (unsigned short*)alloc((size_t)128 * 288 * 2);
    unsigned short* BT1   = (unsigned short*)alloc((size_t)128 * 384 * 2);
    unsigned short* BT2   = (unsigned short*)alloc((size_t)32 * 384 * 2);
    float* outp = (float*)d_out;

    // CSR build
    hipMemsetAsync(cnt, 0, N_NODES * 4, stream);
    hist_kernel<<<(N_EDGES + 255) / 256, 256, 0, stream>>>(ei, cnt, N_EDGES);
    int nb = (N_NODES + 1023) / 1024;
    scan1<<<nb, 256, 0, stream>>>(cnt, off, bsum, N_NODES);
    scan2<<<1, 64, 0, stream>>>(bsum, nb);
    scan3<<<(N_NODES + 1 + 255) / 256, 256, 0, stream>>>(off, bsum, N_NODES, N_EDGES);
    hipMemsetAsync(cnt, 0, N_NODES * 4, stream);
    scatter_kernel<<<(N_EDGES + 255) / 256, 256, 0, stream>>>(ei, wgt, sim, off, cnt,
                                                              edat, N_EDGES);
    // prep
    convert_x<<<(N_NODES * 96 + 255) / 256, 256, 0, stream>>>(x0, xb, N_NODES);
    build_bt<<<(128 * 288 + 255) / 256, 256, 0, stream>>>(wr[0], wi[0], lw[0], BT0, 75, 96, 128);
    build_bt<<<(128 * 384 + 255) / 256, 256, 0, stream>>>(wr[1], wi[1], lw[1], BT1, 128, 128, 128);
    build_bt<<<(32 * 384 + 255) / 256, 256, 0, stream>>>(wr[2], wi[2], lw[2], BT2, 128, 128, 32);

    int agrid = (N_NODES + 3) / 4;

    // layer 0: xb [N,96] -> h1b [N,128]
    agg_bf16<48><<<agrid, 256, 0, stream>>>((const uint32_tt*)xb, off, edat,
                                            (uint32_tt*)aggRb, (uint32_tt*)aggIb, N_NODES);
    gemm_mfma<96, 128, 64, 2, 2, 2, 4, true>
        <<<(N_NODES + 63) / 64, 256, 0, stream>>>(aggRb, aggIb, xb, BT0, cb[0], lb[0],
                                                  h1b, N_NODES);
    // layer 1: h1b [N,128] -> h2b [N,128]
    agg_bf16<64><<<agrid, 256, 0, stream>>>((const uint32_tt*)h1b, off, edat,
                                            (uint32_tt*)aggRb, (uint32_tt*)aggIb, N_NODES);
    gemm_mfma<128, 128, 64, 2, 2, 2, 4, true>
        <<<(N_NODES + 63) / 64, 256, 0, stream>>>(aggRb, aggIb, h1b, BT1, cb[1], lb[1],
                                                  h2b, N_NODES);
    // layer 2: h2b [N,128] -> out [N,32] fp32
    agg_bf16<64><<<agrid, 256, 0, stream>>>((const uint32_tt*)h2b, off, edat,
                                            (uint32_tt*)aggRb, (uint32_tt*)aggIb, N_NODES);
    gemm_mfma<128, 32, 128, 4, 1, 2, 2, false>
        <<<(N_NODES + 127) / 128, 256, 0, stream>>>(aggRb, aggIb, h2b, BT2, cb[2], lb[2],
                                                    outp, N_NODES);
}

// Round 5
// 320.955 us; speedup vs baseline: 1.1004x; 1.1004x over previous
//
#include <hip/hip_runtime.h>

#define N_NODES 50000
#define N_EDGES 600000
#define E_PAD_MAX (N_EDGES + N_NODES * 7)   // padded edge capacity

using bf16x8 = __attribute__((ext_vector_type(8))) short;
using f32x4  = __attribute__((ext_vector_type(4))) float;
typedef unsigned int uint32_tt;

__device__ __forceinline__ unsigned short f2bf(float f) {
    union { float f; unsigned int u; } v; v.f = f;
    unsigned int u = v.u;
    return (unsigned short)((u + 0x7fffu + ((u >> 16) & 1u)) >> 16);  // RNE
}
__device__ __forceinline__ float bf2f(unsigned int h16) {
    union { unsigned int u; float f; } v; v.u = h16 << 16;
    return v.f;
}

// ---------------- CSR build (degrees padded to multiple of 8) ----------------

__global__ void hist_kernel(const int* __restrict__ ei, int* __restrict__ cnt, int E) {
    int e = blockIdx.x * 256 + threadIdx.x;
    if (e < E) atomicAdd(&cnt[ei[E + e]], 1);
}

// scan over PADDED degrees: (deg+7)&~7
__global__ void scan1(const int* __restrict__ deg, int* __restrict__ out,
                      int* __restrict__ bsum, int n) {
    __shared__ int s[256];
    int t = threadIdx.x;
    int base = blockIdx.x * 1024 + t * 4;
    int v0 = (base + 0 < n) ? ((deg[base + 0] + 7) & ~7) : 0;
    int v1 = (base + 1 < n) ? ((deg[base + 1] + 7) & ~7) : 0;
    int v2 = (base + 2 < n) ? ((deg[base + 2] + 7) & ~7) : 0;
    int v3 = (base + 3 < n) ? ((deg[base + 3] + 7) & ~7) : 0;
    int tsum = v0 + v1 + v2 + v3;
    s[t] = tsum;
    __syncthreads();
    for (int off = 1; off < 256; off <<= 1) {
        int tmp = (t >= off) ? s[t - off] : 0;
        __syncthreads();
        s[t] += tmp;
        __syncthreads();
    }
    int excl = s[t] - tsum;
    if (base + 0 < n) out[base + 0] = excl;
    if (base + 1 < n) out[base + 1] = excl + v0;
    if (base + 2 < n) out[base + 2] = excl + v0 + v1;
    if (base + 3 < n) out[base + 3] = excl + v0 + v1 + v2;
    if (t == 255) bsum[blockIdx.x] = s[255];
}

__global__ void scan2(int* __restrict__ bsum, int nb) {
    if (threadIdx.x == 0 && blockIdx.x == 0) {
        int acc = 0;
        for (int i = 0; i < nb; ++i) { int v = bsum[i]; bsum[i] = acc; acc += v; }
        bsum[nb] = acc;   // total padded edge count
    }
}

__global__ void scan3(int* __restrict__ off, const int* __restrict__ bsum, int n, int nb) {
    int i = blockIdx.x * 256 + threadIdx.x;
    if (i < n) off[i] += bsum[i >> 10];
    if (i == n) off[n] = bsum[nb];
}

// packed edge metadata: {src, f32bits(cr), f32bits(ci), 0}; pad slots stay
// all-zero from the edat memset ({src=0, cr=0, ci=0} contributes exactly 0)
__global__ void scatter_kernel(const int* __restrict__ ei, const float* __restrict__ w,
                               const float* __restrict__ sim, const int* __restrict__ off,
                               int* __restrict__ cnt, uint4* __restrict__ edat, int E) {
    int e = blockIdx.x * 256 + threadIdx.x;
    if (e >= E) return;
    int s = ei[e], d = ei[E + e];
    int p = off[d] + atomicAdd(&cnt[d], 1);
    float wt = w[e];
    uint4 m;
    m.x = (unsigned)s;
    m.y = __float_as_uint(wt * sim[2 * e]);
    m.z = __float_as_uint(wt * sim[2 * e + 1]);
    m.w = 0u;
    edat[p] = m;
}

// ---------------- prep: x -> bf16 padded [N][96]; weight pack ----------------

__global__ void convert_x(const float* __restrict__ x0, unsigned short* __restrict__ xb, int n) {
    int i = blockIdx.x * 256 + threadIdx.x;
    if (i >= n * 96) return;
    int r = i / 96, c = i - r * 96;
    xb[i] = (c < 75) ? f2bf(x0[r * 75 + c]) : (unsigned short)0;
}

// BT[n][part*CINP + k] = {wr[k][n], -wi[k][n], lw[n][k]}  (bf16, zero-padded k>=CIN)
__global__ void build_bt(const float* __restrict__ wr, const float* __restrict__ wi,
                         const float* __restrict__ lw, unsigned short* __restrict__ BT,
                         int CIN, int CINP, int COUT) {
    int KTOT = 3 * CINP;
    int i = blockIdx.x * 256 + threadIdx.x;
    if (i >= COUT * KTOT) return;
    int nn = i / KTOT, k = i - nn * KTOT;
    int part = k / CINP, kk = k - part * CINP;
    float v = 0.f;
    if (kk < CIN) {
        if (part == 0)      v = wr[kk * COUT + nn];
        else if (part == 1) v = -wi[kk * COUT + nn];
        else                v = lw[nn * CIN + kk];
    }
    BT[i] = f2bf(v);
}

// ---------------- aggregation: one wave per node, scalarized edge metadata ---
// Edge segments are padded to multiples of 8 (pads contribute exact 0).
// node is readfirstlane'd -> off2/edat loads become s_load (SMEM), src/cr/ci
// become SGPRs -> gather is global_load_dword with SGPR base + loop-invariant
// lane offset (zero per-gather VALU); per-edge VALU = 2 unpack + 4 FMA.
template <int CU2>  // uint32s per feature row (= CINP/2)
__global__ __launch_bounds__(256) void agg_bf16(
    const uint32_tt* __restrict__ x, const int* __restrict__ off,
    const uint4* __restrict__ edat, uint32_tt* __restrict__ aggR,
    uint32_tt* __restrict__ aggI, int n) {
    int wave = threadIdx.x >> 6;
    int lane = threadIdx.x & 63;
    int node = __builtin_amdgcn_readfirstlane(blockIdx.x * 4 + wave);
    if (node >= n) return;
    int lc = (CU2 == 64) ? lane : (lane < CU2 ? lane : CU2 - 1);  // clamped lane
    float arl = 0.f, arh = 0.f, ail = 0.f, aih = 0.f;
    int e0 = off[node], e1 = off[node + 1];

    if (e0 < e1) {
        uint4 m[8];
#pragma unroll
        for (int j = 0; j < 8; ++j) m[j] = edat[e0 + j];
        for (int e = e0; e < e1; e += 8) {
            int   sj[8]; float crj[8], cij[8];
#pragma unroll
            for (int j = 0; j < 8; ++j) {
                sj[j]  = __builtin_amdgcn_readfirstlane((int)m[j].x);
                crj[j] = __uint_as_float(__builtin_amdgcn_readfirstlane((int)m[j].y));
                cij[j] = __uint_as_float(__builtin_amdgcn_readfirstlane((int)m[j].z));
            }
            // 8 independent gathers, SGPR base + invariant lane offset
            uint32_tt w[8];
#pragma unroll
            for (int j = 0; j < 8; ++j) {
                const uint32_tt* rowp = x + (size_t)sj[j] * CU2;
                w[j] = rowp[lc];
            }
            // prefetch next batch's metadata while gathers are in flight
            if (e + 8 < e1) {
#pragma unroll
                for (int j = 0; j < 8; ++j) m[j] = edat[e + 8 + j];
            }
#pragma unroll
            for (int j = 0; j < 8; ++j) {
                float lo = bf2f(w[j] & 0xffffu), hi = bf2f(w[j] >> 16);
                arl += crj[j] * lo; arh += crj[j] * hi;
                ail += cij[j] * lo; aih += cij[j] * hi;
            }
        }
    }
    if (lane < CU2) {
        aggR[(size_t)node * CU2 + lane] = (uint32_tt)f2bf(arl) | ((uint32_tt)f2bf(arh) << 16);
        aggI[(size_t)node * CU2 + lane] = (uint32_tt)f2bf(ail) | ((uint32_tt)f2bf(aih) << 16);
    }
}

// ---------------- bf16 MFMA GEMM: out = relu([aggR|aggI|x] @ BT^T + cb + lb) --
template <int CINP, int COUT, int BM, int WM, int WN, int MT, int NT, bool OUT_BF16>
__global__ __launch_bounds__(256) void gemm_mfma(
    const unsigned short* __restrict__ A0, const unsigned short* __restrict__ A1,
    const unsigned short* __restrict__ A2, const unsigned short* __restrict__ BT,
    const float* __restrict__ cb, const float* __restrict__ lb,
    void* __restrict__ outv, int n) {
    constexpr int PK = 40;              // padded k-stride (bf16): 80B rows -> 2-way banks
    constexpr int KTOT = 3 * CINP;
    constexpr int NCH = KTOT / 32;      // K chunks
    constexpr int CPP = CINP / 32;      // chunks per part
    __shared__ unsigned short sA[BM][PK];
    __shared__ unsigned short sB[COUT][PK];

    int t = threadIdx.x;
    int lane = t & 63, wave = t >> 6;
    int wm = wave / WN, wn = wave % WN;
    int ml = lane & 15, kh = lane >> 4;   // kh in [0,4)
    int node0 = blockIdx.x * BM;

    const unsigned short* Asrc[3] = {A0, A1, A2};

    f32x4 acc[MT][NT];
#pragma unroll
    for (int mt = 0; mt < MT; ++mt)
#pragma unroll
        for (int nt = 0; nt < NT; ++nt) acc[mt][nt] = (f32x4){0.f, 0.f, 0.f, 0.f};

    for (int c = 0; c < NCH; ++c) {
        int part = c / CPP;
        int kk = (c - part * CPP) * 32;
        const unsigned short* __restrict__ Ap = Asrc[part];
        __syncthreads();
#pragma unroll
        for (int i = t; i < BM * 4; i += 256) {
            int r = i >> 2, q = i & 3;
            int node = node0 + r;
            if (node >= n) node = n - 1;  // clamp: garbage rows never written out
            *(uint4*)&sA[r][q * 8] =
                *(const uint4*)(Ap + (size_t)node * CINP + kk + q * 8);
        }
#pragma unroll
        for (int i = t; i < COUT * 4; i += 256) {
            int r = i >> 2, q = i & 3;
            *(uint4*)&sB[r][q * 8] =
                *(const uint4*)(BT + (size_t)r * KTOT + c * 32 + q * 8);
        }
        __syncthreads();
        bf16x8 af[MT], bfr[NT];
#pragma unroll
        for (int mt = 0; mt < MT; ++mt)
            af[mt] = *(const bf16x8*)&sA[wm * (MT * 16) + mt * 16 + ml][kh * 8];
#pragma unroll
        for (int nt = 0; nt < NT; ++nt)
            bfr[nt] = *(const bf16x8*)&sB[wn * (NT * 16) + nt * 16 + ml][kh * 8];
#pragma unroll
        for (int mt = 0; mt < MT; ++mt)
#pragma unroll
            for (int nt = 0; nt < NT; ++nt)
                acc[mt][nt] = __builtin_amdgcn_mfma_f32_16x16x32_bf16(
                    af[mt], bfr[nt], acc[mt][nt], 0, 0, 0);
    }

    // epilogue: C/D layout col=lane&15, row=(lane>>4)*4+reg  [m89-verified]
    int row0 = kh * 4;
#pragma unroll
    for (int nt = 0; nt < NT; ++nt) {
        int col = wn * (NT * 16) + nt * 16 + ml;
        float bias = cb[col] + lb[col];
#pragma unroll
        for (int mt = 0; mt < MT; ++mt) {
#pragma unroll
            for (int r = 0; r < 4; ++r) {
                int node = node0 + wm * (MT * 16) + mt * 16 + row0 + r;
                if (node < n) {
                    float v = acc[mt][nt][r] + bias;
                    v = v > 0.f ? v : 0.f;
                    if (OUT_BF16)
                        ((unsigned short*)outv)[(size_t)node * COUT + col] = f2bf(v);
                    else
                        ((float*)outv)[(size_t)node * COUT + col] = v;
                }
            }
        }
    }
}

// ---------------- launch ----------------

extern "C" void kernel_launch(void* const* d_in, const int* in_sizes, int n_in,
                              void* d_out, int out_size, void* d_ws, size_t ws_size,
                              hipStream_t stream) {
    const float* x0  = (const float*)d_in[0];
    const int*   ei  = (const int*)d_in[1];
    const float* wgt = (const float*)d_in[2];
    const float* sim = (const float*)d_in[3];
    const float *wr[3], *wi[3], *cb[3], *lw[3], *lb[3];
    for (int l = 0; l < 3; ++l) {
        wr[l] = (const float*)d_in[4 + 5 * l];
        wi[l] = (const float*)d_in[5 + 5 * l];
        cb[l] = (const float*)d_in[6 + 5 * l];
        lw[l] = (const float*)d_in[7 + 5 * l];
        lb[l] = (const float*)d_in[8 + 5 * l];
    }

    char* p = (char*)d_ws;
    auto alloc = [&](size_t bytes) -> void* {
        void* r = p;
        p += (bytes + 255) & ~(size_t)255;
        return r;
    };
    int*   off  = (int*)alloc((N_NODES + 1) * 4);
    int*   cnt  = (int*)alloc(N_NODES * 4);
    int*   bsum = (int*)alloc(256);
    uint4* edat = (uint4*)alloc((size_t)E_PAD_MAX * 16);
    unsigned short* xb    = (unsigned short*)alloc((size_t)N_NODES * 96 * 2);
    unsigned short* aggRb = (unsigned short*)alloc((size_t)N_NODES * 128 * 2);
    unsigned short* aggIb = (unsigned short*)alloc((size_t)N_NODES * 128 * 2);
    unsigned short* h1b   = (unsigned short*)alloc((size_t)N_NODES * 128 * 2);
    unsigned short* h2b   = (unsigned short*)alloc((size_t)N_NODES * 128 * 2);
    unsigned short* BT0   = (unsigned short*)alloc((size_t)128 * 288 * 2);
    unsigned short* BT1   = (unsigned short*)alloc((size_t)128 * 384 * 2);
    unsigned short* BT2   = (unsigned short*)alloc((size_t)32 * 384 * 2);
    float* outp = (float*)d_out;

    // CSR build (padded segments; edat pre-zeroed so pad slots are null edges)
    hipMemsetAsync(cnt, 0, N_NODES * 4, stream);
    hipMemsetAsync(edat, 0, (size_t)E_PAD_MAX * 16, stream);
    hist_kernel<<<(N_EDGES + 255) / 256, 256, 0, stream>>>(ei, cnt, N_EDGES);
    int nb = (N_NODES + 1023) / 1024;
    scan1<<<nb, 256, 0, stream>>>(cnt, off, bsum, N_NODES);
    scan2<<<1, 64, 0, stream>>>(bsum, nb);
    scan3<<<(N_NODES + 1 + 255) / 256, 256, 0, stream>>>(off, bsum, N_NODES, nb);
    hipMemsetAsync(cnt, 0, N_NODES * 4, stream);
    scatter_kernel<<<(N_EDGES + 255) / 256, 256, 0, stream>>>(ei, wgt, sim, off, cnt,
                                                              edat, N_EDGES);
    // prep
    convert_x<<<(N_NODES * 96 + 255) / 256, 256, 0, stream>>>(x0, xb, N_NODES);
    build_bt<<<(128 * 288 + 255) / 256, 256, 0, stream>>>(wr[0], wi[0], lw[0], BT0, 75, 96, 128);
    build_bt<<<(128 * 384 + 255) / 256, 256, 0, stream>>>(wr[1], wi[1], lw[1], BT1, 128, 128, 128);
    build_bt<<<(32 * 384 + 255) / 256, 256, 0, stream>>>(wr[2], wi[2], lw[2], BT2, 128, 128, 32);

    int agrid = (N_NODES + 3) / 4;

    // layer 0: xb [N,96] -> h1b [N,128]
    agg_bf16<48><<<agrid, 256, 0, stream>>>((const uint32_tt*)xb, off, edat,
                                            (uint32_tt*)aggRb, (uint32_tt*)aggIb, N_NODES);
    gemm_mfma<96, 128, 64, 2, 2, 2, 4, true>
        <<<(N_NODES + 63) / 64, 256, 0, stream>>>(aggRb, aggIb, xb, BT0, cb[0], lb[0],
                                                  h1b, N_NODES);
    // layer 1: h1b [N,128] -> h2b [N,128]
    agg_bf16<64><<<agrid, 256, 0, stream>>>((const uint32_tt*)h1b, off, edat,
                                            (uint32_tt*)aggRb, (uint32_tt*)aggIb, N_NODES);
    gemm_mfma<128, 128, 64, 2, 2, 2, 4, true>
        <<<(N_NODES + 63) / 64, 256, 0, stream>>>(aggRb, aggIb, h1b, BT1, cb[1], lb[1],
                                                  h2b, N_NODES);
    // layer 2: h2b [N,128] -> out [N,32] fp32
    agg_bf16<64><<<agrid, 256, 0, stream>>>((const uint32_tt*)h2b, off, edat,
                                            (uint32_tt*)aggRb, (uint32_tt*)aggIb, N_NODES);
    gemm_mfma<128, 32, 128, 4, 1, 2, 2, false>
        <<<(N_NODES + 127) / 128, 256, 0, stream>>>(aggRb, aggIb, h2b, BT2, cb[2], lb[2],
                                                    outp, N_NODES);
}